// Round 1
// baseline (159.416 us; speedup 1.0000x reference)
//
#include <hip/hip_runtime.h>

// Problem constants (from reference): B=2, L=2048, H=8, D=64, window=32, stride=64
#define Bc 2
#define Lc 2048
#define Hc 8
#define Dc 64
#define TL 16                 // rows (query positions) per block
#define NT (Lc / TL)          // 128 tiles along L
#define RHD (Hc * Dc)         // 512 floats between consecutive s rows
#define SP1 65                // stride+1
#define SCALE 0.125f          // 1/sqrt(64)

// ---------------------------------------------------------------------------
// Kernel 1: per-(b,h) chunk sums of V over tiles of TL rows -> partials
// partials[bh][t][d] = sum_{s in tile t} V[b,s,h,d]
// ---------------------------------------------------------------------------
__global__ __launch_bounds__(256)
void dozer_chunk_sum(const float* __restrict__ V, float* __restrict__ partials) {
    const int t  = blockIdx.x;
    const int bh = blockIdx.y;
    const int b  = bh >> 3;
    const int h  = bh & 7;
    const int g  = threadIdx.x >> 6;   // 0..3 (wave)
    const int d  = threadIdx.x & 63;
    const float* Vbh = V + (size_t)b * Lc * RHD + h * Dc;
    const int l0 = t * TL;
    float s = 0.f;
    for (int r = g; r < TL; r += 4)
        s += Vbh[(size_t)(l0 + r) * RHD + d];
    __shared__ float red[4][64];
    red[g][d] = s;
    __syncthreads();
    if (g == 0)
        partials[((size_t)bh * NT + t) * 64 + d] =
            red[0][d] + red[1][d] + red[2][d] + red[3][d];
}

// ---------------------------------------------------------------------------
// Kernel 2: main sparse-attention kernel.
// Block = (b,h, tile of TL=16 rows), 256 threads = 4 waves, 4 rows per wave.
// ---------------------------------------------------------------------------
__global__ __launch_bounds__(256)
void dozer_main(const float* __restrict__ Q, const float* __restrict__ K,
                const float* __restrict__ V, const float* __restrict__ partials,
                float* __restrict__ out) {
    const int t    = blockIdx.x;
    const int bh   = blockIdx.y;
    const int b    = bh >> 3;
    const int h    = bh & 7;
    const int tid  = threadIdx.x;
    const int wave = tid >> 6;
    const int lane = tid & 63;
    const int l0   = t * TL;

    const float* Qbh = Q + (size_t)b * Lc * RHD + h * Dc;
    const float* Kbh = K + (size_t)b * Lc * RHD + h * Dc;
    const float* Vbh = V + (size_t)b * Lc * RHD + h * Dc;

    __shared__ float Ptile[TL][64];   // inclusive prefix sums of V for tile rows
    __shared__ float red[4][64];
    __shared__ float wbuf[4][64];     // per-wave sparse weights for current row

    // ---- prefix base: sum of all V rows strictly before l0 ----
    float base = 0.f;
    if (partials) {
        const float* pb = partials + (size_t)bh * NT * 64;
        for (int c = wave; c < t; c += 4)
            base += pb[(size_t)c * 64 + lane];
    } else {
        // fallback if workspace too small: sum V directly
        for (int s = wave; s < l0; s += 4)
            base += Vbh[(size_t)s * RHD + lane];
    }
    red[wave][lane] = base;
    __syncthreads();
    if (wave == 0) {
        float s = red[0][lane] + red[1][lane] + red[2][lane] + red[3][lane];
        for (int r = 0; r < TL; ++r) {
            s += Vbh[(size_t)(l0 + r) * RHD + lane];
            Ptile[r][lane] = s;
        }
    }
    __syncthreads();

    const int p  = lane >> 4;   // position slot within a batch of 4
    const int dd = lane & 15;   // d-quad index (handles d = 4*dd .. 4*dd+3)

    for (int rr = 0; rr < TL / 4; ++rr) {
        const int r = wave * (TL / 4) + rr;
        const int l = l0 + r;
        const int nband = (l + 1 < 17) ? (l + 1) : 17;  // band offsets 0..nband-1
        const int nstr  = l / SP1;                      // strided offsets 65k, k=1..nstr
        const int npos  = nband + nstr;

        // ---- Phase A: compute w_i = exp(scale*dot_i) - 1 for all sparse i ----
        const float4 q4 = *(const float4*)&Qbh[(size_t)l * RHD + dd * 4];
        for (int base_i = 0; base_i < npos; base_i += 4) {
            const int pi = base_i + p;
            const bool ok = (pi < npos);
            int j;
            if (pi < nband) j = l - pi;
            else            j = l - SP1 * (pi - nband + 1);
            float dot = 0.f;
            if (ok) {
                const float4 k4 = *(const float4*)&Kbh[(size_t)j * RHD + dd * 4];
                dot = q4.x * k4.x + q4.y * k4.y + q4.z * k4.z + q4.w * k4.w;
            }
            // reduce the 16 partial sums within this position's lane group
            dot += __shfl_xor(dot, 1, 64);
            dot += __shfl_xor(dot, 2, 64);
            dot += __shfl_xor(dot, 4, 64);
            dot += __shfl_xor(dot, 8, 64);
            const float w = __expf(SCALE * dot) - 1.f;
            if (ok && dd == 0) wbuf[wave][pi] = w;
        }
        // same-wave LDS write->read: DS pipe is in-order per wave; compiler
        // orders via may-alias dependence. No barrier needed (npos varies per wave).

        // ---- Phase B: accumulate numerator/denominator, lane-per-d ----
        float acc = 0.f, den = 0.f;
        for (int i = 0; i < npos; ++i) {
            const float w = wbuf[wave][i];           // broadcast read
            int j;
            if (i < nband) j = l - i;
            else           j = l - SP1 * (i - nband + 1);
            acc += w * Vbh[(size_t)j * RHD + lane];
            den += w;
        }
        const float denom = (float)(l + 1) + den;
        out[((size_t)(b * Lc + l) * Hc + h) * Dc + lane] =
            (Ptile[r][lane] + acc) / denom;
    }
}

// ---------------------------------------------------------------------------
extern "C" void kernel_launch(void* const* d_in, const int* in_sizes, int n_in,
                              void* d_out, int out_size, void* d_ws, size_t ws_size,
                              hipStream_t stream) {
    // inputs: 0=x (unused), 1=queries, 2=keys, 3=values, 4=attn_mask (causal, rebuilt analytically)
    const float* Q = (const float*)d_in[1];
    const float* K = (const float*)d_in[2];
    const float* V = (const float*)d_in[3];
    float* out = (float*)d_out;

    const size_t need = (size_t)Bc * Hc * NT * 64 * sizeof(float);  // 512 KB
    float* partials = (ws_size >= need) ? (float*)d_ws : nullptr;

    dim3 grid(NT, Bc * Hc);
    if (partials)
        dozer_chunk_sum<<<grid, 256, 0, stream>>>(V, partials);
    dozer_main<<<grid, 256, 0, stream>>>(Q, K, V, partials, out);
}

// Round 2
// 127.010 us; speedup vs baseline: 1.2552x; 1.2552x over previous
//
#include <hip/hip_runtime.h>

// Problem constants (from reference): B=2, L=2048, H=8, D=64, window=32, stride=64
#define Bc 2
#define Lc 2048
#define Hc 8
#define Dc 64
#define TL 16                 // rows (query positions) per block
#define NT (Lc / TL)          // 128 tiles along L
#define RHD (Hc * Dc)         // 512 floats between consecutive s rows
#define SP1 65                // stride+1
#define SCALE 0.125f          // 1/sqrt(64)

// ---------------------------------------------------------------------------
// Kernel 1: per-(b,h) chunk sums of V over tiles of TL rows -> partials
// partials[bh][t][d] = sum_{s in tile t} V[b,s,h,d]
// ---------------------------------------------------------------------------
__global__ __launch_bounds__(256)
void dozer_chunk_sum(const float* __restrict__ V, float* __restrict__ partials) {
    const int bh = blockIdx.x;         // grid swapped vs R1: bh fastest
    const int t  = blockIdx.y;
    const int b  = bh >> 3;
    const int h  = bh & 7;
    const int g  = threadIdx.x >> 6;   // 0..3 (wave)
    const int d  = threadIdx.x & 63;
    const float* Vbh = V + (size_t)b * Lc * RHD + h * Dc;
    const int l0 = t * TL;
    float s = 0.f;
    for (int r = g; r < TL; r += 4)
        s += Vbh[(size_t)(l0 + r) * RHD + d];
    __shared__ float red[4][64];
    red[g][d] = s;
    __syncthreads();
    if (g == 0)
        partials[((size_t)bh * NT + t) * 64 + d] =
            red[0][d] + red[1][d] + red[2][d] + red[3][d];
}

// ---------------------------------------------------------------------------
// Kernel 2: main sparse-attention kernel, fused weight+accumulate.
// Block = (bh, tile of TL=16 rows), 256 threads = 4 waves, 4 rows per wave.
// Lane layout inside a wave: p = lane>>4 (position slot 0..3),
//                            dd = lane&15 (d-quad: handles d = 4*dd..4*dd+3).
// grid is (bh=16, t=128) so a CU's resident blocks span varied t -> balanced.
// ---------------------------------------------------------------------------
__global__ __launch_bounds__(256)
void dozer_main(const float* __restrict__ Q, const float* __restrict__ K,
                const float* __restrict__ V, const float* __restrict__ partials,
                float* __restrict__ out) {
    const int bh   = blockIdx.x;
    const int t    = blockIdx.y;
    const int b    = bh >> 3;
    const int h    = bh & 7;
    const int tid  = threadIdx.x;
    const int wave = tid >> 6;
    const int lane = tid & 63;
    const int l0   = t * TL;

    const float* Qbh = Q + (size_t)b * Lc * RHD + h * Dc;
    const float* Kbh = K + (size_t)b * Lc * RHD + h * Dc;
    const float* Vbh = V + (size_t)b * Lc * RHD + h * Dc;

    __shared__ float Ptile[TL][64];   // inclusive prefix sums of V for tile rows
    __shared__ float red[4][64];

    // ---- prefix base: sum of all V rows strictly before l0 ----
    float base = 0.f;
    if (partials) {
        const float* pb = partials + (size_t)bh * NT * 64;
        for (int c = wave; c < t; c += 4)
            base += pb[(size_t)c * 64 + lane];
    } else {
        for (int s = wave; s < l0; s += 4)
            base += Vbh[(size_t)s * RHD + lane];
    }
    red[wave][lane] = base;
    __syncthreads();
    if (wave == 0) {
        float s = red[0][lane] + red[1][lane] + red[2][lane] + red[3][lane];
        for (int r = 0; r < TL; ++r) {
            s += Vbh[(size_t)(l0 + r) * RHD + lane];
            Ptile[r][lane] = s;
        }
    }
    __syncthreads();

    const int p  = lane >> 4;   // position slot within a batch of 4
    const int dd = lane & 15;   // d-quad index

    for (int rr = 0; rr < 4; ++rr) {
        const int r = wave * 4 + rr;
        const int l = l0 + r;
        const int nband = (l + 1 < 17) ? (l + 1) : 17;  // band offsets 0..nband-1
        const int nstr  = l / SP1;                      // strided offsets 65k, k=1..nstr
        const int npos  = nband + nstr;

        const float4 q4 = *(const float4*)&Qbh[(size_t)l * RHD + dd * 4];
        float4 acc = make_float4(0.f, 0.f, 0.f, 0.f);
        float  den = 0.f;

        #pragma unroll 2
        for (int i0 = 0; i0 < npos; i0 += 4) {
            const int pi = i0 + p;
            const bool ok = (pi < npos);
            int j;
            if (pi < nband) j = l - pi;
            else            j = l - SP1 * (pi - nband + 1);
            float dot = 0.f;
            float4 v4 = make_float4(0.f, 0.f, 0.f, 0.f);
            if (ok) {
                const float4 k4 = *(const float4*)&Kbh[(size_t)j * RHD + dd * 4];
                v4 = *(const float4*)&Vbh[(size_t)j * RHD + dd * 4];
                dot = q4.x * k4.x + q4.y * k4.y + q4.z * k4.z + q4.w * k4.w;
            }
            // butterfly within the 16-lane group: all lanes end with full dot
            dot += __shfl_xor(dot, 1, 64);
            dot += __shfl_xor(dot, 2, 64);
            dot += __shfl_xor(dot, 4, 64);
            dot += __shfl_xor(dot, 8, 64);
            const float w = __expf(SCALE * dot) - 1.f;
            if (ok) {
                acc.x += w * v4.x; acc.y += w * v4.y;
                acc.z += w * v4.z; acc.w += w * v4.w;
                den += w;
            }
        }

        // combine across the 4 position groups (swap bits 4,5 of lane)
        acc.x += __shfl_xor(acc.x, 16, 64); acc.x += __shfl_xor(acc.x, 32, 64);
        acc.y += __shfl_xor(acc.y, 16, 64); acc.y += __shfl_xor(acc.y, 32, 64);
        acc.z += __shfl_xor(acc.z, 16, 64); acc.z += __shfl_xor(acc.z, 32, 64);
        acc.w += __shfl_xor(acc.w, 16, 64); acc.w += __shfl_xor(acc.w, 32, 64);
        den   += __shfl_xor(den, 16, 64);   den   += __shfl_xor(den, 32, 64);

        const float inv = 1.f / ((float)(l + 1) + den);
        if (p == 0) {
            const float4 P4 = *(const float4*)&Ptile[r][dd * 4];
            float4 o;
            o.x = (P4.x + acc.x) * inv;
            o.y = (P4.y + acc.y) * inv;
            o.z = (P4.z + acc.z) * inv;
            o.w = (P4.w + acc.w) * inv;
            *(float4*)&out[((size_t)(b * Lc + l) * Hc + h) * Dc + dd * 4] = o;
        }
    }
}

// ---------------------------------------------------------------------------
extern "C" void kernel_launch(void* const* d_in, const int* in_sizes, int n_in,
                              void* d_out, int out_size, void* d_ws, size_t ws_size,
                              hipStream_t stream) {
    // inputs: 0=x (unused), 1=queries, 2=keys, 3=values, 4=attn_mask (causal, analytic)
    const float* Q = (const float*)d_in[1];
    const float* K = (const float*)d_in[2];
    const float* V = (const float*)d_in[3];
    float* out = (float*)d_out;

    const size_t need = (size_t)Bc * Hc * NT * 64 * sizeof(float);  // 512 KB
    float* partials = (ws_size >= need) ? (float*)d_ws : nullptr;

    dim3 grid(Bc * Hc, NT);   // bh fastest: balances per-CU tile mix
    if (partials)
        dozer_chunk_sum<<<grid, 256, 0, stream>>>(V, partials);
    dozer_main<<<grid, 256, 0, stream>>>(Q, K, V, partials, out);
}